// Round 1
// baseline (1704.609 us; speedup 1.0000x reference)
//
#include <hip/hip_runtime.h>
#include <math.h>

#define NN 100000
#define NE 1600000
#define DIN 256
#define DHID 128
#define NCLS 64
#define NEG_SLOPE 0.2f

// ---------------- atomics helpers ----------------
__device__ __forceinline__ void atomicMaxFloat(float* addr, float val) {
    if (val >= 0.f) atomicMax((int*)addr, __float_as_int(val));
    else            atomicMin((unsigned int*)addr, __float_as_uint(val));
}

__device__ __forceinline__ void atomAddF(float* a, float v) {
#if defined(__HIP_DEVICE_COMPILE__)
    unsafeAtomicAdd(a, v);   // HW global_atomic_add_f32 on gfx950
#else
    atomicAdd(a, v);
#endif
}

// ---------------- init kernels ----------------
__global__ void fill_neg_inf(float* p, int n) {
    int i = blockIdx.x * blockDim.x + threadIdx.x;
    if (i < n) p[i] = -INFINITY;
}

// ---------------- GEMM1: feat = X @ W  (100000x256 @ 256x128) ----------------
// block: 256 threads, computes 64 rows x 128 cols. K staged in chunks of 64.
__global__ __launch_bounds__(256) void gemm_feat(const float* __restrict__ X,
                                                 const float* __restrict__ W,
                                                 float* __restrict__ feat) {
    __shared__ float Xs[64][64];    // [k][row]  (transposed store)
    __shared__ float Ws[64][128];   // [k][col]
    const int tid = threadIdx.x;
    const int row0 = blockIdx.x * 64;
    const int ty = tid / 16;   // 0..15 -> row group
    const int tx = tid % 16;   // 0..15 -> col base

    float acc[4][8];
#pragma unroll
    for (int i = 0; i < 4; i++)
#pragma unroll
        for (int j = 0; j < 8; j++) acc[i][j] = 0.f;

    for (int k0 = 0; k0 < DIN; k0 += 64) {
        // load X tile 64 rows x 64 k (transposed into Xs[k][row])
        {
            int r = tid / 4;          // 0..63
            int cq = tid % 4;         // 0..3, each covers 16 k
            int grow = row0 + r;
            const float* gp = X + (size_t)grow * DIN + k0 + cq * 16;
#pragma unroll
            for (int q = 0; q < 4; q++) {
                float4 v = make_float4(0, 0, 0, 0);
                if (grow < NN) v = *(const float4*)(gp + q * 4);
                int kk = cq * 16 + q * 4;
                Xs[kk + 0][r] = v.x;
                Xs[kk + 1][r] = v.y;
                Xs[kk + 2][r] = v.z;
                Xs[kk + 3][r] = v.w;
            }
        }
        // load W tile 64 k x 128 cols
        {
            int cq = tid % 32;        // col quad
            int kr0 = tid / 32;       // 0..7
#pragma unroll
            for (int kr = 0; kr < 8; kr++) {
                int k = kr0 + kr * 8;
                float4 v = *(const float4*)(W + (size_t)(k0 + k) * DHID + cq * 4);
                *(float4*)(&Ws[k][cq * 4]) = v;
            }
        }
        __syncthreads();

#pragma unroll 4
        for (int kk = 0; kk < 64; kk++) {
            float xa[4], wb[8];
#pragma unroll
            for (int i = 0; i < 4; i++) xa[i] = Xs[kk][ty * 4 + i];
#pragma unroll
            for (int j = 0; j < 8; j++) wb[j] = Ws[kk][tx + 16 * j];
#pragma unroll
            for (int i = 0; i < 4; i++)
#pragma unroll
                for (int j = 0; j < 8; j++) acc[i][j] += xa[i] * wb[j];
        }
        __syncthreads();
    }

#pragma unroll
    for (int i = 0; i < 4; i++) {
        int row = row0 + ty * 4 + i;
        if (row < NN) {
            float* op = feat + (size_t)row * DHID;
#pragma unroll
            for (int j = 0; j < 8; j++) op[tx + 16 * j] = acc[i][j];
        }
    }
}

// ---------------- el/er: per-node dot with attn vectors ----------------
__global__ __launch_bounds__(256) void eler_kernel(const float* __restrict__ feat,
                                                   const float* __restrict__ attn_l,
                                                   const float* __restrict__ attn_r,
                                                   float* __restrict__ el,
                                                   float* __restrict__ er) {
    int n = blockIdx.x * 4 + threadIdx.x / 64;
    int lane = threadIdx.x & 63;
    if (n >= NN) return;
    float2 f = ((const float2*)(feat + (size_t)n * DHID))[lane];
    float2 al = ((const float2*)attn_l)[lane];
    float2 ar = ((const float2*)attn_r)[lane];
    float pl = f.x * al.x + f.y * al.y;
    float pr = f.x * ar.x + f.y * ar.y;
#pragma unroll
    for (int off = 32; off; off >>= 1) {
        pl += __shfl_down(pl, off);
        pr += __shfl_down(pr, off);
    }
    if (lane == 0) { el[n] = pl; er[n] = pr; }
}

// ---------------- edge pass 1: e = leaky_relu(el[s]+er[d]); segment max ----------------
__global__ __launch_bounds__(256) void edge_e_kernel(const int* __restrict__ src,
                                                     const int* __restrict__ dst,
                                                     const float* __restrict__ el,
                                                     const float* __restrict__ er,
                                                     float* __restrict__ abuf,
                                                     float* __restrict__ m) {
    int i = blockIdx.x * blockDim.x + threadIdx.x;
    if (i >= NE) return;
    int s = src[i], d = dst[i];
    float x = el[s] + er[d];
    float e = x > 0.f ? x : NEG_SLOPE * x;
    abuf[i] = e;
    atomicMaxFloat(&m[d], e);
}

// ---------------- edge pass 2: ex = exp(e - m[d]); segment sum ----------------
__global__ __launch_bounds__(256) void edge_exp_kernel(const int* __restrict__ dst,
                                                       const float* __restrict__ m,
                                                       float* __restrict__ abuf,
                                                       float* __restrict__ denom) {
    int i = blockIdx.x * blockDim.x + threadIdx.x;
    if (i >= NE) return;
    int d = dst[i];
    float ex = expf(abuf[i] - m[d]);
    abuf[i] = ex;
    atomAddF(&denom[d], ex);
}

// ---------------- edge pass 3: h[d] += ex * feat[s]  (wave per edge) ----------------
__global__ __launch_bounds__(256) void scatter_kernel(const int* __restrict__ src,
                                                      const int* __restrict__ dst,
                                                      const float* __restrict__ abuf,
                                                      const float* __restrict__ feat,
                                                      float* __restrict__ h) {
    int e = blockIdx.x * 4 + threadIdx.x / 64;
    int lane = threadIdx.x & 63;
    if (e >= NE) return;
    int s = src[e], d = dst[e];
    float ex = abuf[e];
    float2 f = ((const float2*)(feat + (size_t)s * DHID))[lane];
    float* hp = h + (size_t)d * DHID + 2 * lane;
    atomAddF(hp + 0, ex * f.x);
    atomAddF(hp + 1, ex * f.y);
}

// ---------------- GEMM2: out = (h/denom) @ fcW + fcb ----------------
__global__ __launch_bounds__(256) void gemm_out(const float* __restrict__ h,
                                                const float* __restrict__ denom,
                                                const float* __restrict__ fcW,
                                                const float* __restrict__ fcb,
                                                float* __restrict__ out) {
    __shared__ float Ws[DHID * NCLS];   // 32 KB
    __shared__ float hs[4][DHID];
    const int tid = threadIdx.x;
    // cooperative load of fcW
    for (int i = tid; i < DHID * NCLS / 4; i += 256)
        ((float4*)Ws)[i] = ((const float4*)fcW)[i];

    int row0 = blockIdx.x * 4;
    int r = tid / 64;
    int lane = tid % 64;
    int row = row0 + r;
    float2 hv = make_float2(0.f, 0.f);
    float inv = 0.f;
    if (row < NN) {
        float dn = denom[row];
        inv = dn > 0.f ? 1.0f / dn : 0.0f;
        hv = ((const float2*)(h + (size_t)row * DHID))[lane];
    }
    hs[r][2 * lane + 0] = hv.x * inv;
    hs[r][2 * lane + 1] = hv.y * inv;
    __syncthreads();

    float acc = fcb[lane];
#pragma unroll 8
    for (int k = 0; k < DHID; k++) acc += hs[r][k] * Ws[k * NCLS + lane];
    if (row < NN) out[(size_t)row * NCLS + lane] = acc;
}

// ---------------- launch ----------------
extern "C" void kernel_launch(void* const* d_in, const int* in_sizes, int n_in,
                              void* d_out, int out_size, void* d_ws, size_t ws_size,
                              hipStream_t stream) {
    const float* X      = (const float*)d_in[0];
    const float* W      = (const float*)d_in[1];
    const float* attn_l = (const float*)d_in[2];
    const float* attn_r = (const float*)d_in[3];
    const float* fcW    = (const float*)d_in[4];
    const float* fcb    = (const float*)d_in[5];
    const int*   src    = (const int*)d_in[6];
    const int*   dst    = (const int*)d_in[7];
    float* out = (float*)d_out;

    float* ws = (float*)d_ws;
    float* feat  = ws;                    // NN*128
    float* el    = feat + (size_t)NN * DHID;  // NN
    float* er    = el + NN;               // NN
    float* m     = er + NN;               // NN
    float* denom = m + NN;                // NN
    float* h     = denom + NN;            // NN*128
    float* abuf  = h + (size_t)NN * DHID; // NE

    // init accumulators (must be per-call: graph replays)
    hipMemsetAsync(h, 0, (size_t)NN * DHID * sizeof(float), stream);
    hipMemsetAsync(denom, 0, (size_t)NN * sizeof(float), stream);
    fill_neg_inf<<<(NN + 255) / 256, 256, 0, stream>>>(m, NN);

    gemm_feat<<<(NN + 63) / 64, 256, 0, stream>>>(X, W, feat);
    eler_kernel<<<(NN + 3) / 4, 256, 0, stream>>>(feat, attn_l, attn_r, el, er);
    edge_e_kernel<<<(NE + 255) / 256, 256, 0, stream>>>(src, dst, el, er, abuf, m);
    edge_exp_kernel<<<(NE + 255) / 256, 256, 0, stream>>>(dst, m, abuf, denom);
    scatter_kernel<<<(NE + 3) / 4, 256, 0, stream>>>(src, dst, abuf, feat, h);
    gemm_out<<<(NN + 3) / 4, 256, 0, stream>>>(h, denom, fcW, fcb, out);
}

// Round 2
// 496.976 us; speedup vs baseline: 3.4300x; 3.4300x over previous
//
#include <hip/hip_runtime.h>
#include <math.h>

#define NN 100000
#define NE 1600000
#define DIN 256
#define DHID 128
#define NCLS 64
#define NEG_SLOPE 0.2f

#define NBS 98   // ceil(NN / 1024)

// ---------------- CSR build ----------------
__global__ __launch_bounds__(256) void k_deg_count(const int* __restrict__ dst,
                                                   int* __restrict__ deg) {
    int i = blockIdx.x * blockDim.x + threadIdx.x;
    if (i < NE) atomicAdd(&deg[dst[i]], 1);
}

__global__ __launch_bounds__(256) void k_blocksum(const int* __restrict__ deg,
                                                  int* __restrict__ bsum) {
    int b = blockIdx.x, tid = threadIdx.x;
    int base = b * 1024 + tid * 4;
    int s = 0;
#pragma unroll
    for (int q = 0; q < 4; q++) {
        int i = base + q;
        if (i < NN) s += deg[i];
    }
    __shared__ int sh[256];
    sh[tid] = s;
    __syncthreads();
    for (int o = 128; o; o >>= 1) {
        if (tid < o) sh[tid] += sh[tid + o];
        __syncthreads();
    }
    if (tid == 0) bsum[b] = sh[0];
}

__global__ void k_scan_bsum(const int* __restrict__ bsum, int* __restrict__ boff) {
    if (threadIdx.x == 0 && blockIdx.x == 0) {
        int run = 0;
        for (int i = 0; i < NBS; i++) { boff[i] = run; run += bsum[i]; }
    }
}

__global__ __launch_bounds__(256) void k_local_scan(const int* __restrict__ deg,
                                                    const int* __restrict__ boff,
                                                    int* __restrict__ off) {
    int b = blockIdx.x, tid = threadIdx.x;
    int base = b * 1024 + tid * 4;
    int v[4];
    int tsum = 0;
#pragma unroll
    for (int q = 0; q < 4; q++) {
        v[q] = (base + q < NN) ? deg[base + q] : 0;
        tsum += v[q];
    }
    __shared__ int sh[256];
    sh[tid] = tsum;
    __syncthreads();
    for (int d = 1; d < 256; d <<= 1) {
        int add = (tid >= d) ? sh[tid - d] : 0;
        __syncthreads();
        sh[tid] += add;
        __syncthreads();
    }
    int run = sh[tid] - tsum + boff[b];   // exclusive prefix for this thread
#pragma unroll
    for (int q = 0; q < 4; q++) {
        if (base + q < NN) off[base + q] = run;
        run += v[q];
    }
}

__global__ __launch_bounds__(256) void k_fill(const int* __restrict__ src,
                                              const int* __restrict__ dst,
                                              const int* __restrict__ off,
                                              int* __restrict__ cnt2,
                                              int* __restrict__ ssrc) {
    int i = blockIdx.x * blockDim.x + threadIdx.x;
    if (i >= NE) return;
    int d = dst[i];
    int pos = off[d] + atomicAdd(&cnt2[d], 1);
    ssrc[pos] = src[i];
}

// ---------------- GEMM1: feat = X @ W  (100000x256 @ 256x128) ----------------
__global__ __launch_bounds__(256) void gemm_feat(const float* __restrict__ X,
                                                 const float* __restrict__ W,
                                                 float* __restrict__ feat) {
    __shared__ float Xs[64][64];    // [k][row]
    __shared__ float Ws[64][128];   // [k][col]
    const int tid = threadIdx.x;
    const int row0 = blockIdx.x * 64;
    const int ty = tid / 16;
    const int tx = tid % 16;

    float acc[4][8];
#pragma unroll
    for (int i = 0; i < 4; i++)
#pragma unroll
        for (int j = 0; j < 8; j++) acc[i][j] = 0.f;

    for (int k0 = 0; k0 < DIN; k0 += 64) {
        {
            int r = tid / 4;
            int cq = tid % 4;
            int grow = row0 + r;
            const float* gp = X + (size_t)grow * DIN + k0 + cq * 16;
#pragma unroll
            for (int q = 0; q < 4; q++) {
                float4 v = make_float4(0, 0, 0, 0);
                if (grow < NN) v = *(const float4*)(gp + q * 4);
                int kk = cq * 16 + q * 4;
                Xs[kk + 0][r] = v.x;
                Xs[kk + 1][r] = v.y;
                Xs[kk + 2][r] = v.z;
                Xs[kk + 3][r] = v.w;
            }
        }
        {
            int cq = tid % 32;
            int kr0 = tid / 32;
#pragma unroll
            for (int kr = 0; kr < 8; kr++) {
                int k = kr0 + kr * 8;
                float4 v = *(const float4*)(W + (size_t)(k0 + k) * DHID + cq * 4);
                *(float4*)(&Ws[k][cq * 4]) = v;
            }
        }
        __syncthreads();

#pragma unroll 4
        for (int kk = 0; kk < 64; kk++) {
            float xa[4], wb[8];
#pragma unroll
            for (int i = 0; i < 4; i++) xa[i] = Xs[kk][ty * 4 + i];
#pragma unroll
            for (int j = 0; j < 8; j++) wb[j] = Ws[kk][tx + 16 * j];
#pragma unroll
            for (int i = 0; i < 4; i++)
#pragma unroll
                for (int j = 0; j < 8; j++) acc[i][j] += xa[i] * wb[j];
        }
        __syncthreads();
    }

#pragma unroll
    for (int i = 0; i < 4; i++) {
        int row = row0 + ty * 4 + i;
        if (row < NN) {
            float* op = feat + (size_t)row * DHID;
#pragma unroll
            for (int j = 0; j < 8; j++) op[tx + 16 * j] = acc[i][j];
        }
    }
}

// ---------------- el/er ----------------
__global__ __launch_bounds__(256) void eler_kernel(const float* __restrict__ feat,
                                                   const float* __restrict__ attn_l,
                                                   const float* __restrict__ attn_r,
                                                   float* __restrict__ el,
                                                   float* __restrict__ er) {
    int n = blockIdx.x * 4 + threadIdx.x / 64;
    int lane = threadIdx.x & 63;
    if (n >= NN) return;
    float2 f = ((const float2*)(feat + (size_t)n * DHID))[lane];
    float2 al = ((const float2*)attn_l)[lane];
    float2 ar = ((const float2*)attn_r)[lane];
    float pl = f.x * al.x + f.y * al.y;
    float pr = f.x * ar.x + f.y * ar.y;
#pragma unroll
    for (int off = 32; off; off >>= 1) {
        pl += __shfl_down(pl, off);
        pr += __shfl_down(pr, off);
    }
    if (lane == 0) { el[n] = pl; er[n] = pr; }
}

// ---------------- fused softmax + aggregate: one wave per dst node ----------------
__global__ __launch_bounds__(256) void aggregate(const int* __restrict__ off,
                                                 const int* __restrict__ deg,
                                                 const int* __restrict__ ssrc,
                                                 const float* __restrict__ el,
                                                 const float* __restrict__ er,
                                                 const float* __restrict__ feat,
                                                 float* __restrict__ h) {
    int d = blockIdx.x * 4 + threadIdx.x / 64;
    int lane = threadIdx.x & 63;
    if (d >= NN) return;
    int start = off[d];
    int dg = deg[d];
    float erd = er[d];

    // pass 1: segment max
    float m = -INFINITY;
    for (int j = lane; j < dg; j += 64) {
        int s = ssrc[start + j];
        float x = el[s] + erd;
        float e = x > 0.f ? x : NEG_SLOPE * x;
        m = fmaxf(m, e);
    }
#pragma unroll
    for (int o = 32; o; o >>= 1) m = fmaxf(m, __shfl_xor(m, o));

    // pass 2: exp weights, denom, weighted feat accumulation
    float2 acc = make_float2(0.f, 0.f);
    float denom = 0.f;
    for (int c = 0; c < dg; c += 64) {
        int j = c + lane;
        float w = 0.f;
        int s = 0;
        if (j < dg) {
            s = ssrc[start + j];
            float x = el[s] + erd;
            float e = x > 0.f ? x : NEG_SLOPE * x;
            w = expf(e - m);
        }
        float wsum = w;
#pragma unroll
        for (int o = 32; o; o >>= 1) wsum += __shfl_xor(wsum, o);
        denom += wsum;

        int rem = dg - c;
        if (rem > 64) rem = 64;
        int jj = 0;
        for (; jj + 1 < rem; jj += 2) {
            float w0 = __shfl(w, jj), w1 = __shfl(w, jj + 1);
            int s0 = __shfl(s, jj), s1 = __shfl(s, jj + 1);
            float2 f0 = ((const float2*)(feat + (size_t)s0 * DHID))[lane];
            float2 f1 = ((const float2*)(feat + (size_t)s1 * DHID))[lane];
            acc.x += w0 * f0.x + w1 * f1.x;
            acc.y += w0 * f0.y + w1 * f1.y;
        }
        if (jj < rem) {
            float w0 = __shfl(w, jj);
            int s0 = __shfl(s, jj);
            float2 f0 = ((const float2*)(feat + (size_t)s0 * DHID))[lane];
            acc.x += w0 * f0.x;
            acc.y += w0 * f0.y;
        }
    }
    float inv = (dg > 0) ? 1.0f / denom : 0.f;
    ((float2*)(h + (size_t)d * DHID))[lane] = make_float2(acc.x * inv, acc.y * inv);
}

// ---------------- GEMM2: out = h @ fcW + fcb (h pre-normalized) ----------------
__global__ __launch_bounds__(256) void gemm_out(const float* __restrict__ h,
                                                const float* __restrict__ fcW,
                                                const float* __restrict__ fcb,
                                                float* __restrict__ out) {
    __shared__ float Ws[DHID * NCLS];   // 32 KB
    __shared__ float hs[4][DHID];
    const int tid = threadIdx.x;
    for (int i = tid; i < DHID * NCLS / 4; i += 256)
        ((float4*)Ws)[i] = ((const float4*)fcW)[i];

    int row0 = blockIdx.x * 4;
    int r = tid / 64;
    int lane = tid % 64;
    int row = row0 + r;
    float2 hv = make_float2(0.f, 0.f);
    if (row < NN) hv = ((const float2*)(h + (size_t)row * DHID))[lane];
    hs[r][2 * lane + 0] = hv.x;
    hs[r][2 * lane + 1] = hv.y;
    __syncthreads();

    float acc = fcb[lane];
#pragma unroll 8
    for (int k = 0; k < DHID; k++) acc += hs[r][k] * Ws[k * NCLS + lane];
    if (row < NN) out[(size_t)row * NCLS + lane] = acc;
}

// ---------------- launch ----------------
extern "C" void kernel_launch(void* const* d_in, const int* in_sizes, int n_in,
                              void* d_out, int out_size, void* d_ws, size_t ws_size,
                              hipStream_t stream) {
    const float* X      = (const float*)d_in[0];
    const float* W      = (const float*)d_in[1];
    const float* attn_l = (const float*)d_in[2];
    const float* attn_r = (const float*)d_in[3];
    const float* fcW    = (const float*)d_in[4];
    const float* fcb    = (const float*)d_in[5];
    const int*   src    = (const int*)d_in[6];
    const int*   dst    = (const int*)d_in[7];
    float* out = (float*)d_out;

    char* ws = (char*)d_ws;
    float* feat = (float*)ws;                       ws += (size_t)NN * DHID * 4;
    float* h    = (float*)ws;                       ws += (size_t)NN * DHID * 4;
    float* el   = (float*)ws;                       ws += (size_t)NN * 4;
    float* er   = (float*)ws;                       ws += (size_t)NN * 4;
    int*   deg  = (int*)ws;                         ws += (size_t)NN * 4;
    int*   off  = (int*)ws;                         ws += (size_t)NN * 4;
    int*   cnt2 = (int*)ws;                         ws += (size_t)NN * 4;
    int*   bsum = (int*)ws;                         ws += (size_t)128 * 4;
    int*   boff = (int*)ws;                         ws += (size_t)128 * 4;
    int*   ssrc = (int*)ws;                         ws += (size_t)NE * 4;

    // per-call init (graph replays)
    hipMemsetAsync(deg, 0, (size_t)NN * sizeof(int), stream);
    hipMemsetAsync(cnt2, 0, (size_t)NN * sizeof(int), stream);

    // CSR build
    k_deg_count<<<(NE + 255) / 256, 256, 0, stream>>>(dst, deg);
    k_blocksum<<<NBS, 256, 0, stream>>>(deg, bsum);
    k_scan_bsum<<<1, 64, 0, stream>>>(bsum, boff);
    k_local_scan<<<NBS, 256, 0, stream>>>(deg, boff, off);
    k_fill<<<(NE + 255) / 256, 256, 0, stream>>>(src, dst, off, cnt2, ssrc);

    // dense pipeline
    gemm_feat<<<(NN + 63) / 64, 256, 0, stream>>>(X, W, feat);
    eler_kernel<<<(NN + 3) / 4, 256, 0, stream>>>(feat, attn_l, attn_r, el, er);
    aggregate<<<(NN + 3) / 4, 256, 0, stream>>>(off, deg, ssrc, el, er, feat, h);
    gemm_out<<<(NN + 3) / 4, 256, 0, stream>>>(h, fcW, fcb, out);
}

// Round 3
// 360.449 us; speedup vs baseline: 4.7291x; 1.3788x over previous
//
#include <hip/hip_runtime.h>
#include <math.h>

#define NN 100000
#define NE 1600000
#define DIN 256
#define DHID 128
#define NCLS 64
#define NEG_SLOPE 0.2f
#define NBS 98   // ceil(NN / 1024)

typedef __bf16 bf16_t;
typedef bf16_t bf16x8 __attribute__((ext_vector_type(8)));
typedef float f32x4 __attribute__((ext_vector_type(4)));

__device__ __forceinline__ ushort f2bf(float f) {
    union { float f; unsigned u; } c; c.f = f;
    unsigned u = c.u;
    unsigned r = (u + 0x7FFFu + ((u >> 16) & 1u)) >> 16;
    return (ushort)r;
}
__device__ __forceinline__ float bf2f(ushort b) {
    return __uint_as_float(((unsigned)b) << 16);
}

// ---------------- CSR build ----------------
__global__ __launch_bounds__(256) void k_deg_count(const int* __restrict__ dst,
                                                   int* __restrict__ deg) {
    int i = blockIdx.x * blockDim.x + threadIdx.x;
    if (i < NE) atomicAdd(&deg[dst[i]], 1);
}

__global__ __launch_bounds__(256) void k_blocksum(const int* __restrict__ deg,
                                                  int* __restrict__ bsum) {
    int b = blockIdx.x, tid = threadIdx.x;
    int base = b * 1024 + tid * 4;
    int s = 0;
#pragma unroll
    for (int q = 0; q < 4; q++) {
        int i = base + q;
        if (i < NN) s += deg[i];
    }
    __shared__ int sh[256];
    sh[tid] = s;
    __syncthreads();
    for (int o = 128; o; o >>= 1) {
        if (tid < o) sh[tid] += sh[tid + o];
        __syncthreads();
    }
    if (tid == 0) bsum[b] = sh[0];
}

__global__ void k_scan_bsum(const int* __restrict__ bsum, int* __restrict__ boff) {
    if (threadIdx.x == 0 && blockIdx.x == 0) {
        int run = 0;
        for (int i = 0; i < NBS; i++) { boff[i] = run; run += bsum[i]; }
    }
}

__global__ __launch_bounds__(256) void k_local_scan(const int* __restrict__ deg,
                                                    const int* __restrict__ boff,
                                                    int* __restrict__ off) {
    int b = blockIdx.x, tid = threadIdx.x;
    int base = b * 1024 + tid * 4;
    int v[4];
    int tsum = 0;
#pragma unroll
    for (int q = 0; q < 4; q++) {
        v[q] = (base + q < NN) ? deg[base + q] : 0;
        tsum += v[q];
    }
    __shared__ int sh[256];
    sh[tid] = tsum;
    __syncthreads();
    for (int d = 1; d < 256; d <<= 1) {
        int add = (tid >= d) ? sh[tid - d] : 0;
        __syncthreads();
        sh[tid] += add;
        __syncthreads();
    }
    int run = sh[tid] - tsum + boff[b];
#pragma unroll
    for (int q = 0; q < 4; q++) {
        if (base + q < NN) off[base + q] = run;
        run += v[q];
    }
}

__global__ __launch_bounds__(256) void k_fill(const int* __restrict__ src,
                                              const int* __restrict__ dst,
                                              const int* __restrict__ off,
                                              int* __restrict__ cnt2,
                                              int* __restrict__ ssrc) {
    int i = blockIdx.x * blockDim.x + threadIdx.x;
    if (i >= NE) return;
    int d = dst[i];
    int pos = off[d] + atomicAdd(&cnt2[d], 1);
    ssrc[pos] = src[i];
}

// ---------------- prep: transpose+convert weights to bf16 ----------------
__global__ __launch_bounds__(256) void k_prep(const float* __restrict__ W,
                                              const float* __restrict__ fcW,
                                              ushort* __restrict__ Wt,
                                              ushort* __restrict__ fcWt) {
    int t = blockIdx.x * 256 + threadIdx.x;
    for (int i = t; i < DHID * DIN; i += gridDim.x * 256) {   // Wt[n][k]
        int n = i >> 8, k = i & 255;
        Wt[i] = f2bf(W[k * DHID + n]);
    }
    for (int i = t; i < NCLS * DHID; i += gridDim.x * 256) {  // fcWt[n][k]
        int n = i >> 7, k = i & 127;
        fcWt[i] = f2bf(fcW[k * NCLS + n]);
    }
}

// ---------------- GEMM1: featb = bf16(X) @ bf16(W), MFMA ----------------
// block: 256 thr (4 waves), tile 128 rows x 128 cols, K=256 one-shot in LDS.
__global__ __launch_bounds__(256) void gemm1(const float* __restrict__ X,
                                             const ushort* __restrict__ Wt,
                                             ushort* __restrict__ featb) {
    __shared__ ushort Xs[128 * 256];   // 64 KB [row][k] bf16, XOR-swizzled
    __shared__ ushort Wl[128 * 256];   // 64 KB [n][k]  bf16, XOR-swizzled
    const int t = threadIdx.x;
    const int row0 = blockIdx.x * 128;

    // stage X: fp32 -> bf16, perfect-coalesced global, swizzled LDS
    {
        const float4* gx = (const float4*)X;   // 64 float4 per row
#pragma unroll
        for (int i = 0; i < 32; i++) {
            int f = i * 256 + t;               // float4 index in 128x256 tile
            int row = f >> 6;
            int grow = row0 + row;
            float4 v = make_float4(0.f, 0.f, 0.f, 0.f);
            if (grow < NN) v = gx[(size_t)grow * 64 + (f & 63)];
            ushort4 b;
            b.x = f2bf(v.x); b.y = f2bf(v.y); b.z = f2bf(v.z); b.w = f2bf(v.w);
            int byte_off = row * 512 + ((((f & 63) * 8)) ^ ((row & 7) << 4));
            *(ushort4*)((char*)Xs + byte_off) = b;
        }
    }
    // stage Wt: bf16 copy with swizzle (4096 x 16B)
    {
        const uint4* gw = (const uint4*)Wt;
#pragma unroll
        for (int i = 0; i < 16; i++) {
            int u = i * 256 + t;
            int n = u >> 5;                    // 32 x 16B per 512B row
            int byte_off = n * 512 + (((u & 31) * 16) ^ ((n & 7) << 4));
            *(uint4*)((char*)Wl + byte_off) = gw[u];
        }
    }
    __syncthreads();

    const int w = t >> 6, lane = t & 63;
    const int rbase = w * 32;
    const int lcol = lane & 15;
    const int kgrp = (lane >> 4) * 16;   // byte offset of this lane's k-group

    f32x4 acc[2][8];
#pragma unroll
    for (int r = 0; r < 2; r++)
#pragma unroll
        for (int c = 0; c < 8; c++) acc[r][c] = (f32x4){0.f, 0.f, 0.f, 0.f};

#pragma unroll
    for (int k0 = 0; k0 < 8; k0++) {
        int kbyte = k0 * 64 + kgrp;
        bf16x8 a[2], b[8];
#pragma unroll
        for (int r = 0; r < 2; r++) {
            int row = rbase + r * 16 + lcol;
            a[r] = *(bf16x8*)((char*)Xs + row * 512 + (kbyte ^ ((row & 7) << 4)));
        }
#pragma unroll
        for (int c = 0; c < 8; c++) {
            int n = c * 16 + lcol;
            b[c] = *(bf16x8*)((char*)Wl + n * 512 + (kbyte ^ ((n & 7) << 4)));
        }
#pragma unroll
        for (int r = 0; r < 2; r++)
#pragma unroll
            for (int c = 0; c < 8; c++)
                acc[r][c] = __builtin_amdgcn_mfma_f32_16x16x32_bf16(a[r], b[c], acc[r][c], 0, 0, 0);
    }

    // epilogue: stage tile bf16 in LDS (reuse Xs), then coalesced store
    __syncthreads();
    ushort* Os = Xs;
#pragma unroll
    for (int r = 0; r < 2; r++)
#pragma unroll
        for (int c = 0; c < 8; c++)
#pragma unroll
            for (int i = 0; i < 4; i++) {
                int rloc = rbase + r * 16 + (lane >> 4) * 4 + i;
                int col = c * 16 + lcol;
                Os[rloc * 128 + col] = f2bf(acc[r][c][i]);
            }
    __syncthreads();
#pragma unroll
    for (int i = 0; i < 8; i++) {
        int u = i * 256 + t;                   // 16B unit; 16 per 256B row
        int row = u >> 4;
        int grow = row0 + row;
        if (grow < NN)
            *(uint4*)(featb + (size_t)grow * 128 + (u & 15) * 8) =
                *(uint4*)((char*)Os + u * 16);
    }
}

// ---------------- el/er from bf16 feat ----------------
__global__ __launch_bounds__(256) void eler_b(const ushort* __restrict__ featb,
                                              const float* __restrict__ attn_l,
                                              const float* __restrict__ attn_r,
                                              float* __restrict__ el,
                                              float* __restrict__ er) {
    int n = blockIdx.x * 4 + threadIdx.x / 64;
    int lane = threadIdx.x & 63;
    if (n >= NN) return;
    ushort2 f = ((const ushort2*)(featb + (size_t)n * DHID))[lane];
    float f0 = bf2f(f.x), f1 = bf2f(f.y);
    float2 al = ((const float2*)attn_l)[lane];
    float2 ar = ((const float2*)attn_r)[lane];
    float pl = f0 * al.x + f1 * al.y;
    float pr = f0 * ar.x + f1 * ar.y;
#pragma unroll
    for (int off = 32; off; off >>= 1) {
        pl += __shfl_down(pl, off);
        pr += __shfl_down(pr, off);
    }
    if (lane == 0) { el[n] = pl; er[n] = pr; }
}

// ---------------- fused softmax + aggregate: one wave per dst node ----------------
__global__ __launch_bounds__(256) void aggregate(const int* __restrict__ off,
                                                 const int* __restrict__ deg,
                                                 const int* __restrict__ ssrc,
                                                 const float* __restrict__ el,
                                                 const float* __restrict__ er,
                                                 const ushort* __restrict__ featb,
                                                 ushort* __restrict__ hb) {
    int d = blockIdx.x * 4 + threadIdx.x / 64;
    int lane = threadIdx.x & 63;
    if (d >= NN) return;
    int start = off[d];
    int dg = deg[d];
    float erd = er[d];

    float m = -INFINITY;
    for (int j = lane; j < dg; j += 64) {
        int s = ssrc[start + j];
        float x = el[s] + erd;
        float e = x > 0.f ? x : NEG_SLOPE * x;
        m = fmaxf(m, e);
    }
#pragma unroll
    for (int o = 32; o; o >>= 1) m = fmaxf(m, __shfl_xor(m, o));

    float2 acc = make_float2(0.f, 0.f);
    float denom = 0.f;
    for (int c = 0; c < dg; c += 64) {
        int j = c + lane;
        float wv = 0.f;
        int s = 0;
        if (j < dg) {
            s = ssrc[start + j];
            float x = el[s] + erd;
            float e = x > 0.f ? x : NEG_SLOPE * x;
            wv = expf(e - m);
        }
        float wsum = wv;
#pragma unroll
        for (int o = 32; o; o >>= 1) wsum += __shfl_xor(wsum, o);
        denom += wsum;

        int rem = dg - c;
        if (rem > 64) rem = 64;
        int jj = 0;
        for (; jj + 1 < rem; jj += 2) {
            float w0 = __shfl(wv, jj), w1 = __shfl(wv, jj + 1);
            int s0 = __shfl(s, jj), s1 = __shfl(s, jj + 1);
            ushort2 g0 = ((const ushort2*)(featb + (size_t)s0 * DHID))[lane];
            ushort2 g1 = ((const ushort2*)(featb + (size_t)s1 * DHID))[lane];
            acc.x += w0 * bf2f(g0.x) + w1 * bf2f(g1.x);
            acc.y += w0 * bf2f(g0.y) + w1 * bf2f(g1.y);
        }
        if (jj < rem) {
            float w0 = __shfl(wv, jj);
            int s0 = __shfl(s, jj);
            ushort2 g0 = ((const ushort2*)(featb + (size_t)s0 * DHID))[lane];
            acc.x += w0 * bf2f(g0.x);
            acc.y += w0 * bf2f(g0.y);
        }
    }
    float inv = (dg > 0) ? 1.0f / denom : 0.f;
    ushort2 o2;
    o2.x = f2bf(acc.x * inv);
    o2.y = f2bf(acc.y * inv);
    ((ushort2*)(hb + (size_t)d * DHID))[lane] = o2;
}

// ---------------- GEMM2: out = bf16(h) @ bf16(fcW) + fcb, MFMA ----------------
__global__ __launch_bounds__(256) void gemm2(const ushort* __restrict__ hb,
                                             const ushort* __restrict__ fcWt,
                                             const float* __restrict__ fcb,
                                             float* __restrict__ out) {
    __shared__ ushort Hs[128 * 128];   // 32 KB [row][k] swizzled
    __shared__ ushort Fs[64 * 128];    // 16 KB [n][k] swizzled
    __shared__ float  Os[128 * 64];    // 32 KB output staging
    const int t = threadIdx.x;
    const int row0 = blockIdx.x * 128;

    {
#pragma unroll
        for (int i = 0; i < 8; i++) {   // 2048 x 16B
            int u = i * 256 + t;
            int row = u >> 4;
            int grow = row0 + row;
            uint4 v = make_uint4(0, 0, 0, 0);
            if (grow < NN) v = *(const uint4*)(hb + (size_t)grow * 128 + (u & 15) * 8);
            int byte_off = row * 256 + (((u & 15) * 16) ^ ((row & 7) << 4));
            *(uint4*)((char*)Hs + byte_off) = v;
        }
#pragma unroll
        for (int i = 0; i < 4; i++) {   // 1024 x 16B
            int u = i * 256 + t;
            int n = u >> 4;
            int byte_off = n * 256 + (((u & 15) * 16) ^ ((n & 7) << 4));
            *(uint4*)((char*)Fs + byte_off) = ((const uint4*)fcWt)[u];
        }
    }
    __syncthreads();

    const int w = t >> 6, lane = t & 63;
    const int rbase = w * 32;
    const int lcol = lane & 15;
    const int kgrp = (lane >> 4) * 16;

    f32x4 acc[2][4];
#pragma unroll
    for (int r = 0; r < 2; r++)
#pragma unroll
        for (int c = 0; c < 4; c++) acc[r][c] = (f32x4){0.f, 0.f, 0.f, 0.f};

#pragma unroll
    for (int k0 = 0; k0 < 4; k0++) {
        int kbyte = k0 * 64 + kgrp;
        bf16x8 a[2], b[4];
#pragma unroll
        for (int r = 0; r < 2; r++) {
            int row = rbase + r * 16 + lcol;
            a[r] = *(bf16x8*)((char*)Hs + row * 256 + (kbyte ^ ((row & 7) << 4)));
        }
#pragma unroll
        for (int c = 0; c < 4; c++) {
            int n = c * 16 + lcol;
            b[c] = *(bf16x8*)((char*)Fs + n * 256 + (kbyte ^ ((n & 7) << 4)));
        }
#pragma unroll
        for (int r = 0; r < 2; r++)
#pragma unroll
            for (int c = 0; c < 4; c++)
                acc[r][c] = __builtin_amdgcn_mfma_f32_16x16x32_bf16(a[r], b[c], acc[r][c], 0, 0, 0);
    }

#pragma unroll
    for (int r = 0; r < 2; r++)
#pragma unroll
        for (int c = 0; c < 4; c++) {
            int col = c * 16 + lcol;
            float bias = fcb[col];
#pragma unroll
            for (int i = 0; i < 4; i++) {
                int rloc = rbase + r * 16 + (lane >> 4) * 4 + i;
                Os[rloc * 64 + col] = acc[r][c][i] + bias;
            }
        }
    __syncthreads();
#pragma unroll
    for (int i = 0; i < 8; i++) {        // 2048 float4
        int u = i * 256 + t;
        int row = u >> 4;
        int grow = row0 + row;
        if (grow < NN)
            *(float4*)(out + (size_t)grow * 64 + (u & 15) * 4) = ((float4*)Os)[u];
    }
}

// ---------------- launch ----------------
extern "C" void kernel_launch(void* const* d_in, const int* in_sizes, int n_in,
                              void* d_out, int out_size, void* d_ws, size_t ws_size,
                              hipStream_t stream) {
    const float* X      = (const float*)d_in[0];
    const float* W      = (const float*)d_in[1];
    const float* attn_l = (const float*)d_in[2];
    const float* attn_r = (const float*)d_in[3];
    const float* fcW    = (const float*)d_in[4];
    const float* fcb    = (const float*)d_in[5];
    const int*   src    = (const int*)d_in[6];
    const int*   dst    = (const int*)d_in[7];
    float* out = (float*)d_out;

    char* ws = (char*)d_ws;
    ushort* featb = (ushort*)ws;            ws += (size_t)NN * DHID * 2;
    ushort* hb    = (ushort*)ws;            ws += (size_t)NN * DHID * 2;
    ushort* Wt    = (ushort*)ws;            ws += (size_t)DHID * DIN * 2;
    ushort* fcWt  = (ushort*)ws;            ws += (size_t)NCLS * DHID * 2;
    float* el     = (float*)ws;             ws += (size_t)NN * 4;
    float* er     = (float*)ws;             ws += (size_t)NN * 4;
    int*   deg    = (int*)ws;               ws += (size_t)NN * 4;
    int*   off    = (int*)ws;               ws += (size_t)NN * 4;
    int*   cnt2   = (int*)ws;               ws += (size_t)NN * 4;
    int*   bsum   = (int*)ws;               ws += (size_t)128 * 4;
    int*   boff   = (int*)ws;               ws += (size_t)128 * 4;
    int*   ssrc   = (int*)ws;               ws += (size_t)NE * 4;

    hipMemsetAsync(deg, 0, (size_t)NN * sizeof(int), stream);
    hipMemsetAsync(cnt2, 0, (size_t)NN * sizeof(int), stream);

    // CSR build + weight prep
    k_deg_count<<<(NE + 255) / 256, 256, 0, stream>>>(dst, deg);
    k_prep<<<64, 256, 0, stream>>>(W, fcW, Wt, fcWt);
    k_blocksum<<<NBS, 256, 0, stream>>>(deg, bsum);
    k_scan_bsum<<<1, 64, 0, stream>>>(bsum, boff);
    k_local_scan<<<NBS, 256, 0, stream>>>(deg, boff, off);
    k_fill<<<(NE + 255) / 256, 256, 0, stream>>>(src, dst, off, cnt2, ssrc);

    // dense pipeline (bf16 MFMA)
    gemm1<<<(NN + 127) / 128, 256, 0, stream>>>(X, Wt, featb);
    eler_b<<<(NN + 3) / 4, 256, 0, stream>>>(featb, attn_l, attn_r, el, er);
    aggregate<<<(NN + 3) / 4, 256, 0, stream>>>(off, deg, ssrc, el, er, featb, hb);
    gemm2<<<(NN + 127) / 128, 256, 0, stream>>>(hb, fcWt, fcb, out);
}

// Round 4
// 232.642 us; speedup vs baseline: 7.3272x; 1.5494x over previous
//
#include <hip/hip_runtime.h>
#include <math.h>

#define NN 100000
#define NE 1600000
#define DIN 256
#define DHID 128
#define NCLS 64
#define NEG_SLOPE 0.2f

#define NBUCK 196          // ceil(NN / 512), bucket = dst >> 9
#define CHUNK 4096
#define NCHB ((NE + CHUNK - 1) / CHUNK)   // 391

typedef __bf16 bf16_t;
typedef bf16_t bf16x8 __attribute__((ext_vector_type(8)));
typedef float f32x4 __attribute__((ext_vector_type(4)));

__device__ __forceinline__ ushort f2bf(float f) {
    union { float f; unsigned u; } c; c.f = f;
    unsigned u = c.u;
    unsigned r = (u + 0x7FFFu + ((u >> 16) & 1u)) >> 16;
    return (ushort)r;
}
__device__ __forceinline__ float bf2f(ushort b) {
    return __uint_as_float(((unsigned)b) << 16);
}

// ================= CSR build: bucketed counting sort =================
// edge packed as ((dst & 511) << 17) | src   (src < 2^17, dst_local < 2^9)

__global__ __launch_bounds__(256) void k_ghist(const int* __restrict__ dst,
                                               int* __restrict__ ghist) {
    __shared__ int h[NBUCK];
    int t = threadIdx.x;
    for (int i = t; i < NBUCK; i += 256) h[i] = 0;
    __syncthreads();
    int base = blockIdx.x * CHUNK;
    int end = base + CHUNK; if (end > NE) end = NE;
    for (int idx = base + t; idx < end; idx += 256)
        atomicAdd(&h[dst[idx] >> 9], 1);
    __syncthreads();
    for (int i = t; i < NBUCK; i += 256)
        if (h[i]) atomicAdd(&ghist[i], h[i]);
}

__global__ __launch_bounds__(256) void k_gscan(const int* __restrict__ ghist,
                                               int* __restrict__ boff,
                                               int* __restrict__ gcur) {
    __shared__ int sh[256];
    int t = threadIdx.x;
    int v = (t < NBUCK) ? ghist[t] : 0;
    sh[t] = v;
    __syncthreads();
    for (int d = 1; d < 256; d <<= 1) {
        int a = (t >= d) ? sh[t - d] : 0;
        __syncthreads();
        sh[t] += a;
        __syncthreads();
    }
    if (t < NBUCK) {
        int ex = sh[t] - v;
        boff[t] = ex;
        gcur[t] = ex;
        if (t == NBUCK - 1) boff[NBUCK] = sh[t];
    }
}

__global__ __launch_bounds__(256) void k_bin(const int* __restrict__ src,
                                             const int* __restrict__ dst,
                                             int* __restrict__ gcur,
                                             unsigned* __restrict__ ebuf) {
    __shared__ int hist[NBUCK];
    __shared__ int scn[256];
    __shared__ int loff[NBUCK];
    __shared__ int cur[NBUCK];
    __shared__ int gb[NBUCK];
    __shared__ unsigned ord[CHUNK];
    __shared__ ushort obk[CHUNK];
    const int t = threadIdx.x;
    const int base = blockIdx.x * CHUNK;
    int cnt = NE - base; if (cnt > CHUNK) cnt = CHUNK;

    for (int i = t; i < NBUCK; i += 256) hist[i] = 0;
    __syncthreads();

    unsigned vals[16];
    int bks[16];
#pragma unroll
    for (int i = 0; i < 16; i++) {
        int idx = base + i * 256 + t;
        if (idx < NE) {
            int d = dst[idx], s = src[idx];
            int bb = d >> 9;
            bks[i] = bb;
            vals[i] = ((unsigned)(d & 511) << 17) | (unsigned)s;
            atomicAdd(&hist[bb], 1);
        } else bks[i] = -1;
    }
    __syncthreads();

    int hv = (t < NBUCK) ? hist[t] : 0;
    scn[t] = hv;
    __syncthreads();
    for (int d = 1; d < 256; d <<= 1) {
        int a = (t >= d) ? scn[t - d] : 0;
        __syncthreads();
        scn[t] += a;
        __syncthreads();
    }
    if (t < NBUCK) { loff[t] = scn[t] - hv; cur[t] = scn[t] - hv; }
    __syncthreads();

#pragma unroll
    for (int i = 0; i < 16; i++) {
        if (bks[i] >= 0) {
            int slot = atomicAdd(&cur[bks[i]], 1);
            ord[slot] = vals[i];
            obk[slot] = (ushort)bks[i];
        }
    }
    if (t < NBUCK && hv > 0) gb[t] = atomicAdd(&gcur[t], hv);
    __syncthreads();

    for (int s = t; s < cnt; s += 256) {
        int bb = obk[s];
        ebuf[gb[bb] + (s - loff[bb])] = ord[s];
    }
}

// one block per bucket: per-node deg/offsets in LDS, local scatter
__global__ __launch_bounds__(256) void k_csr(const unsigned* __restrict__ ebuf,
                                             const int* __restrict__ boff,
                                             int* __restrict__ off_g,
                                             int* __restrict__ deg_g,
                                             int* __restrict__ ssrc) {
    __shared__ int sdeg[512];
    __shared__ int pr[256];
    __shared__ int lofs[512];
    __shared__ int scnt[512];
    const int b = blockIdx.x, t = threadIdx.x;
    const int node0 = b << 9;
    const int ebase = boff[b];
    const int ecnt = boff[b + 1] - ebase;

    sdeg[t] = 0; sdeg[t + 256] = 0;
    __syncthreads();
    for (int s = t; s < ecnt; s += 256)
        atomicAdd(&sdeg[ebuf[ebase + s] >> 17], 1);
    __syncthreads();

    int d0 = sdeg[2 * t], d1 = sdeg[2 * t + 1];
    pr[t] = d0 + d1;
    __syncthreads();
    for (int d = 1; d < 256; d <<= 1) {
        int a = (t >= d) ? pr[t - d] : 0;
        __syncthreads();
        pr[t] += a;
        __syncthreads();
    }
    int ex = pr[t] - d0 - d1;
    lofs[2 * t] = ex;
    lofs[2 * t + 1] = ex + d0;
    scnt[2 * t] = 0; scnt[2 * t + 1] = 0;
    int n0 = node0 + 2 * t, n1 = n0 + 1;
    if (n0 < NN) { off_g[n0] = ebase + ex;      deg_g[n0] = d0; }
    if (n1 < NN) { off_g[n1] = ebase + ex + d0; deg_g[n1] = d1; }
    __syncthreads();

    for (int s = t; s < ecnt; s += 256) {
        unsigned v = ebuf[ebase + s];
        int dl = v >> 17;
        int c = atomicAdd(&scnt[dl], 1);
        ssrc[ebase + lofs[dl] + c] = (int)(v & 0x1FFFFu);
    }
}

// ---------------- prep: transpose+convert weights to bf16 ----------------
__global__ __launch_bounds__(256) void k_prep(const float* __restrict__ W,
                                              const float* __restrict__ fcW,
                                              ushort* __restrict__ Wt,
                                              ushort* __restrict__ fcWt) {
    int t = blockIdx.x * 256 + threadIdx.x;
    for (int i = t; i < DHID * DIN; i += gridDim.x * 256) {   // Wt[n][k]
        int n = i >> 8, k = i & 255;
        Wt[i] = f2bf(W[k * DHID + n]);
    }
    for (int i = t; i < NCLS * DHID; i += gridDim.x * 256) {  // fcWt[n][k]
        int n = i >> 7, k = i & 127;
        fcWt[i] = f2bf(fcW[k * NCLS + n]);
    }
}

// ---------------- GEMM1: featb = bf16(X) @ bf16(W), MFMA ----------------
__global__ __launch_bounds__(256) void gemm1(const float* __restrict__ X,
                                             const ushort* __restrict__ Wt,
                                             ushort* __restrict__ featb) {
    __shared__ ushort Xs[128 * 256];   // 64 KB [row][k] bf16, XOR-swizzled
    __shared__ ushort Wl[128 * 256];   // 64 KB [n][k]  bf16, XOR-swizzled
    const int t = threadIdx.x;
    const int row0 = blockIdx.x * 128;

    {
        const float4* gx = (const float4*)X;
#pragma unroll
        for (int i = 0; i < 32; i++) {
            int f = i * 256 + t;
            int row = f >> 6;
            int grow = row0 + row;
            float4 v = make_float4(0.f, 0.f, 0.f, 0.f);
            if (grow < NN) v = gx[(size_t)grow * 64 + (f & 63)];
            ushort4 bq;
            bq.x = f2bf(v.x); bq.y = f2bf(v.y); bq.z = f2bf(v.z); bq.w = f2bf(v.w);
            int byte_off = row * 512 + ((((f & 63) * 8)) ^ ((row & 7) << 4));
            *(ushort4*)((char*)Xs + byte_off) = bq;
        }
    }
    {
        const uint4* gw = (const uint4*)Wt;
#pragma unroll
        for (int i = 0; i < 16; i++) {
            int u = i * 256 + t;
            int n = u >> 5;
            int byte_off = n * 512 + (((u & 31) * 16) ^ ((n & 7) << 4));
            *(uint4*)((char*)Wl + byte_off) = gw[u];
        }
    }
    __syncthreads();

    const int w = t >> 6, lane = t & 63;
    const int rbase = w * 32;
    const int lcol = lane & 15;
    const int kgrp = (lane >> 4) * 16;

    f32x4 acc[2][8];
#pragma unroll
    for (int r = 0; r < 2; r++)
#pragma unroll
        for (int c = 0; c < 8; c++) acc[r][c] = (f32x4){0.f, 0.f, 0.f, 0.f};

#pragma unroll
    for (int k0 = 0; k0 < 8; k0++) {
        int kbyte = k0 * 64 + kgrp;
        bf16x8 a[2], b[8];
#pragma unroll
        for (int r = 0; r < 2; r++) {
            int row = rbase + r * 16 + lcol;
            a[r] = *(bf16x8*)((char*)Xs + row * 512 + (kbyte ^ ((row & 7) << 4)));
        }
#pragma unroll
        for (int c = 0; c < 8; c++) {
            int n = c * 16 + lcol;
            b[c] = *(bf16x8*)((char*)Wl + n * 512 + (kbyte ^ ((n & 7) << 4)));
        }
#pragma unroll
        for (int r = 0; r < 2; r++)
#pragma unroll
            for (int c = 0; c < 8; c++)
                acc[r][c] = __builtin_amdgcn_mfma_f32_16x16x32_bf16(a[r], b[c], acc[r][c], 0, 0, 0);
    }

    __syncthreads();
    ushort* Os = Xs;
#pragma unroll
    for (int r = 0; r < 2; r++)
#pragma unroll
        for (int c = 0; c < 8; c++)
#pragma unroll
            for (int i = 0; i < 4; i++) {
                int rloc = rbase + r * 16 + (lane >> 4) * 4 + i;
                int col = c * 16 + lcol;
                Os[rloc * 128 + col] = f2bf(acc[r][c][i]);
            }
    __syncthreads();
#pragma unroll
    for (int i = 0; i < 8; i++) {
        int u = i * 256 + t;
        int row = u >> 4;
        int grow = row0 + row;
        if (grow < NN)
            *(uint4*)(featb + (size_t)grow * 128 + (u & 15) * 8) =
                *(uint4*)((char*)Os + u * 16);
    }
}

// ---------------- el/er from bf16 feat ----------------
__global__ __launch_bounds__(256) void eler_b(const ushort* __restrict__ featb,
                                              const float* __restrict__ attn_l,
                                              const float* __restrict__ attn_r,
                                              float* __restrict__ el,
                                              float* __restrict__ er) {
    int n = blockIdx.x * 4 + threadIdx.x / 64;
    int lane = threadIdx.x & 63;
    if (n >= NN) return;
    ushort2 f = ((const ushort2*)(featb + (size_t)n * DHID))[lane];
    float f0 = bf2f(f.x), f1 = bf2f(f.y);
    float2 al = ((const float2*)attn_l)[lane];
    float2 ar = ((const float2*)attn_r)[lane];
    float pl = f0 * al.x + f1 * al.y;
    float pr = f0 * ar.x + f1 * ar.y;
#pragma unroll
    for (int off = 32; off; off >>= 1) {
        pl += __shfl_down(pl, off);
        pr += __shfl_down(pr, off);
    }
    if (lane == 0) { el[n] = pl; er[n] = pr; }
}

// ---------------- fused softmax + aggregate: one wave per dst node ----------------
__global__ __launch_bounds__(256) void aggregate(const int* __restrict__ off,
                                                 const int* __restrict__ deg,
                                                 const int* __restrict__ ssrc,
                                                 const float* __restrict__ el,
                                                 const float* __restrict__ er,
                                                 const ushort* __restrict__ featb,
                                                 ushort* __restrict__ hb) {
    int d = blockIdx.x * 4 + threadIdx.x / 64;
    int lane = threadIdx.x & 63;
    if (d >= NN) return;
    int start = off[d];
    int dg = deg[d];
    float erd = er[d];

    float m = -INFINITY;
    for (int j = lane; j < dg; j += 64) {
        int s = ssrc[start + j];
        float x = el[s] + erd;
        float e = x > 0.f ? x : NEG_SLOPE * x;
        m = fmaxf(m, e);
    }
#pragma unroll
    for (int o = 32; o; o >>= 1) m = fmaxf(m, __shfl_xor(m, o));

    float2 acc = make_float2(0.f, 0.f);
    float denom = 0.f;
    for (int c = 0; c < dg; c += 64) {
        int j = c + lane;
        float wv = 0.f;
        int s = 0;
        if (j < dg) {
            s = ssrc[start + j];
            float x = el[s] + erd;
            float e = x > 0.f ? x : NEG_SLOPE * x;
            wv = expf(e - m);
        }
        float wsum = wv;
#pragma unroll
        for (int o = 32; o; o >>= 1) wsum += __shfl_xor(wsum, o);
        denom += wsum;

        int rem = dg - c;
        if (rem > 64) rem = 64;
        int jj = 0;
        for (; jj + 1 < rem; jj += 2) {
            float w0 = __shfl(wv, jj), w1 = __shfl(wv, jj + 1);
            int s0 = __shfl(s, jj), s1 = __shfl(s, jj + 1);
            ushort2 g0 = ((const ushort2*)(featb + (size_t)s0 * DHID))[lane];
            ushort2 g1 = ((const ushort2*)(featb + (size_t)s1 * DHID))[lane];
            acc.x += w0 * bf2f(g0.x) + w1 * bf2f(g1.x);
            acc.y += w0 * bf2f(g0.y) + w1 * bf2f(g1.y);
        }
        if (jj < rem) {
            float w0 = __shfl(wv, jj);
            int s0 = __shfl(s, jj);
            ushort2 g0 = ((const ushort2*)(featb + (size_t)s0 * DHID))[lane];
            acc.x += w0 * bf2f(g0.x);
            acc.y += w0 * bf2f(g0.y);
        }
    }
    float inv = (dg > 0) ? 1.0f / denom : 0.f;
    ushort2 o2;
    o2.x = f2bf(acc.x * inv);
    o2.y = f2bf(acc.y * inv);
    ((ushort2*)(hb + (size_t)d * DHID))[lane] = o2;
}

// ---------------- GEMM2: out = bf16(h) @ bf16(fcW) + fcb, MFMA ----------------
__global__ __launch_bounds__(256) void gemm2(const ushort* __restrict__ hb,
                                             const ushort* __restrict__ fcWt,
                                             const float* __restrict__ fcb,
                                             float* __restrict__ out) {
    __shared__ ushort Hs[128 * 128];
    __shared__ ushort Fs[64 * 128];
    __shared__ float  Os[128 * 64];
    const int t = threadIdx.x;
    const int row0 = blockIdx.x * 128;

    {
#pragma unroll
        for (int i = 0; i < 8; i++) {
            int u = i * 256 + t;
            int row = u >> 4;
            int grow = row0 + row;
            uint4 v = make_uint4(0, 0, 0, 0);
            if (grow < NN) v = *(const uint4*)(hb + (size_t)grow * 128 + (u & 15) * 8);
            int byte_off = row * 256 + (((u & 15) * 16) ^ ((row & 7) << 4));
            *(uint4*)((char*)Hs + byte_off) = v;
        }
#pragma unroll
        for (int i = 0; i < 4; i++) {
            int u = i * 256 + t;
            int n = u >> 4;
            int byte_off = n * 256 + (((u & 15) * 16) ^ ((n & 7) << 4));
            *(uint4*)((char*)Fs + byte_off) = ((const uint4*)fcWt)[u];
        }
    }
    __syncthreads();

    const int w = t >> 6, lane = t & 63;
    const int rbase = w * 32;
    const int lcol = lane & 15;
    const int kgrp = (lane >> 4) * 16;

    f32x4 acc[2][4];
#pragma unroll
    for (int r = 0; r < 2; r++)
#pragma unroll
        for (int c = 0; c < 4; c++) acc[r][c] = (f32x4){0.f, 0.f, 0.f, 0.f};

#pragma unroll
    for (int k0 = 0; k0 < 4; k0++) {
        int kbyte = k0 * 64 + kgrp;
        bf16x8 a[2], b[4];
#pragma unroll
        for (int r = 0; r < 2; r++) {
            int row = rbase + r * 16 + lcol;
            a[r] = *(bf16x8*)((char*)Hs + row * 256 + (kbyte ^ ((row & 7) << 4)));
        }
#pragma unroll
        for (int c = 0; c < 4; c++) {
            int n = c * 16 + lcol;
            b[c] = *(bf16x8*)((char*)Fs + n * 256 + (kbyte ^ ((n & 7) << 4)));
        }
#pragma unroll
        for (int r = 0; r < 2; r++)
#pragma unroll
            for (int c = 0; c < 4; c++)
                acc[r][c] = __builtin_amdgcn_mfma_f32_16x16x32_bf16(a[r], b[c], acc[r][c], 0, 0, 0);
    }

#pragma unroll
    for (int r = 0; r < 2; r++)
#pragma unroll
        for (int c = 0; c < 4; c++) {
            int col = c * 16 + lcol;
            float bias = fcb[col];
#pragma unroll
            for (int i = 0; i < 4; i++) {
                int rloc = rbase + r * 16 + (lane >> 4) * 4 + i;
                Os[rloc * 64 + col] = acc[r][c][i] + bias;
            }
        }
    __syncthreads();
#pragma unroll
    for (int i = 0; i < 8; i++) {
        int u = i * 256 + t;
        int row = u >> 4;
        int grow = row0 + row;
        if (grow < NN)
            *(float4*)(out + (size_t)grow * 64 + (u & 15) * 4) = ((float4*)Os)[u];
    }
}

// ---------------- launch ----------------
extern "C" void kernel_launch(void* const* d_in, const int* in_sizes, int n_in,
                              void* d_out, int out_size, void* d_ws, size_t ws_size,
                              hipStream_t stream) {
    const float* X      = (const float*)d_in[0];
    const float* W      = (const float*)d_in[1];
    const float* attn_l = (const float*)d_in[2];
    const float* attn_r = (const float*)d_in[3];
    const float* fcW    = (const float*)d_in[4];
    const float* fcb    = (const float*)d_in[5];
    const int*   src    = (const int*)d_in[6];
    const int*   dst    = (const int*)d_in[7];
    float* out = (float*)d_out;

    char* ws = (char*)d_ws;
    ushort* featb = (ushort*)ws;            ws += (size_t)NN * DHID * 2;
    ushort* hb    = (ushort*)ws;            ws += (size_t)NN * DHID * 2;
    ushort* Wt    = (ushort*)ws;            ws += (size_t)DHID * DIN * 2;
    ushort* fcWt  = (ushort*)ws;            ws += (size_t)NCLS * DHID * 2;
    float* el     = (float*)ws;             ws += (size_t)NN * 4;
    float* er     = (float*)ws;             ws += (size_t)NN * 4;
    int*   deg    = (int*)ws;               ws += (size_t)NN * 4;
    int*   off    = (int*)ws;               ws += (size_t)NN * 4;
    int*   ssrc   = (int*)ws;               ws += (size_t)NE * 4;
    unsigned* ebuf = (unsigned*)ws;         ws += (size_t)NE * 4;
    int*   ghist  = (int*)ws;               ws += (size_t)256 * 4;
    int*   boff   = (int*)ws;               ws += (size_t)256 * 4;
    int*   gcur   = (int*)ws;               ws += (size_t)256 * 4;

    hipMemsetAsync(ghist, 0, NBUCK * sizeof(int), stream);

    // CSR build (bucketed counting sort)
    k_ghist<<<NCHB, 256, 0, stream>>>(dst, ghist);
    k_prep<<<64, 256, 0, stream>>>(W, fcW, Wt, fcWt);
    k_gscan<<<1, 256, 0, stream>>>(ghist, boff, gcur);
    k_bin<<<NCHB, 256, 0, stream>>>(src, dst, gcur, ebuf);
    k_csr<<<NBUCK, 256, 0, stream>>>(ebuf, boff, off, deg, ssrc);

    // dense pipeline (bf16 MFMA)
    gemm1<<<(NN + 127) / 128, 256, 0, stream>>>(X, Wt, featb);
    eler_b<<<(NN + 3) / 4, 256, 0, stream>>>(featb, attn_l, attn_r, el, er);
    aggregate<<<(NN + 3) / 4, 256, 0, stream>>>(off, deg, ssrc, el, er, featb, hb);
    gemm2<<<(NN + 127) / 128, 256, 0, stream>>>(hb, fcWt, fcb, out);
}

// Round 5
// 202.701 us; speedup vs baseline: 8.4095x; 1.1477x over previous
//
#include <hip/hip_runtime.h>
#include <math.h>

#define NN 100000
#define NE 1600000
#define DIN 256
#define DHID 128
#define NCLS 64
#define NEG_SLOPE 0.2f

#define NBUCK 196          // ceil(NN / 512), bucket = dst >> 9
#define CHUNK 4096
#define NCHB ((NE + CHUNK - 1) / CHUNK)   // 391

typedef __bf16 bf16_t;
typedef bf16_t bf16x8 __attribute__((ext_vector_type(8)));
typedef float f32x4 __attribute__((ext_vector_type(4)));
typedef ushort ushort8v __attribute__((ext_vector_type(8)));

__device__ __forceinline__ ushort f2bf(float f) {
    union { float f; unsigned u; } c; c.f = f;
    unsigned u = c.u;
    unsigned r = (u + 0x7FFFu + ((u >> 16) & 1u)) >> 16;
    return (ushort)r;
}
__device__ __forceinline__ float bf2f(ushort b) {
    return __uint_as_float(((unsigned)b) << 16);
}

// ================= CSR build: bucketed counting sort =================
__global__ __launch_bounds__(256) void k_ghist(const int* __restrict__ dst,
                                               int* __restrict__ ghist) {
    __shared__ int h[NBUCK];
    int t = threadIdx.x;
    for (int i = t; i < NBUCK; i += 256) h[i] = 0;
    __syncthreads();
    int base = blockIdx.x * CHUNK;
    int end = base + CHUNK; if (end > NE) end = NE;
    for (int idx = base + t; idx < end; idx += 256)
        atomicAdd(&h[dst[idx] >> 9], 1);
    __syncthreads();
    for (int i = t; i < NBUCK; i += 256)
        if (h[i]) atomicAdd(&ghist[i], h[i]);
}

__global__ __launch_bounds__(256) void k_gscan(const int* __restrict__ ghist,
                                               int* __restrict__ boff,
                                               int* __restrict__ gcur) {
    __shared__ int sh[256];
    int t = threadIdx.x;
    int v = (t < NBUCK) ? ghist[t] : 0;
    sh[t] = v;
    __syncthreads();
    for (int d = 1; d < 256; d <<= 1) {
        int a = (t >= d) ? sh[t - d] : 0;
        __syncthreads();
        sh[t] += a;
        __syncthreads();
    }
    if (t < NBUCK) {
        int ex = sh[t] - v;
        boff[t] = ex;
        gcur[t] = ex;
        if (t == NBUCK - 1) boff[NBUCK] = sh[t];
    }
}

__global__ __launch_bounds__(256) void k_bin(const int* __restrict__ src,
                                             const int* __restrict__ dst,
                                             int* __restrict__ gcur,
                                             unsigned* __restrict__ ebuf) {
    __shared__ int hist[NBUCK];
    __shared__ int scn[256];
    __shared__ int loff[NBUCK];
    __shared__ int cur[NBUCK];
    __shared__ int gb[NBUCK];
    __shared__ unsigned ord[CHUNK];
    __shared__ ushort obk[CHUNK];
    const int t = threadIdx.x;
    const int base = blockIdx.x * CHUNK;
    int cnt = NE - base; if (cnt > CHUNK) cnt = CHUNK;

    for (int i = t; i < NBUCK; i += 256) hist[i] = 0;
    __syncthreads();

    unsigned vals[16];
    int bks[16];
#pragma unroll
    for (int i = 0; i < 16; i++) {
        int idx = base + i * 256 + t;
        if (idx < NE) {
            int d = dst[idx], s = src[idx];
            int bb = d >> 9;
            bks[i] = bb;
            vals[i] = ((unsigned)(d & 511) << 17) | (unsigned)s;
            atomicAdd(&hist[bb], 1);
        } else bks[i] = -1;
    }
    __syncthreads();

    int hv = (t < NBUCK) ? hist[t] : 0;
    scn[t] = hv;
    __syncthreads();
    for (int d = 1; d < 256; d <<= 1) {
        int a = (t >= d) ? scn[t - d] : 0;
        __syncthreads();
        scn[t] += a;
        __syncthreads();
    }
    if (t < NBUCK) { loff[t] = scn[t] - hv; cur[t] = scn[t] - hv; }
    __syncthreads();

#pragma unroll
    for (int i = 0; i < 16; i++) {
        if (bks[i] >= 0) {
            int slot = atomicAdd(&cur[bks[i]], 1);
            ord[slot] = vals[i];
            obk[slot] = (ushort)bks[i];
        }
    }
    if (t < NBUCK && hv > 0) gb[t] = atomicAdd(&gcur[t], hv);
    __syncthreads();

    for (int s = t; s < cnt; s += 256) {
        int bb = obk[s];
        ebuf[gb[bb] + (s - loff[bb])] = ord[s];
    }
}

__global__ __launch_bounds__(256) void k_csr(const unsigned* __restrict__ ebuf,
                                             const int* __restrict__ boff,
                                             int* __restrict__ off_g,
                                             int* __restrict__ deg_g,
                                             int* __restrict__ ssrc) {
    __shared__ int sdeg[512];
    __shared__ int pr[256];
    __shared__ int lofs[512];
    __shared__ int scnt[512];
    const int b = blockIdx.x, t = threadIdx.x;
    const int node0 = b << 9;
    const int ebase = boff[b];
    const int ecnt = boff[b + 1] - ebase;

    sdeg[t] = 0; sdeg[t + 256] = 0;
    __syncthreads();
    for (int s = t; s < ecnt; s += 256)
        atomicAdd(&sdeg[ebuf[ebase + s] >> 17], 1);
    __syncthreads();

    int d0 = sdeg[2 * t], d1 = sdeg[2 * t + 1];
    pr[t] = d0 + d1;
    __syncthreads();
    for (int d = 1; d < 256; d <<= 1) {
        int a = (t >= d) ? pr[t - d] : 0;
        __syncthreads();
        pr[t] += a;
        __syncthreads();
    }
    int ex = pr[t] - d0 - d1;
    lofs[2 * t] = ex;
    lofs[2 * t + 1] = ex + d0;
    scnt[2 * t] = 0; scnt[2 * t + 1] = 0;
    int n0 = node0 + 2 * t, n1 = n0 + 1;
    if (n0 < NN) { off_g[n0] = ebase + ex;      deg_g[n0] = d0; }
    if (n1 < NN) { off_g[n1] = ebase + ex + d0; deg_g[n1] = d1; }
    __syncthreads();

    for (int s = t; s < ecnt; s += 256) {
        unsigned v = ebuf[ebase + s];
        int dl = v >> 17;
        int c = atomicAdd(&scnt[dl], 1);
        ssrc[ebase + lofs[dl] + c] = (int)(v & 0x1FFFFu);
    }
}

// ---------------- prep: transpose+convert weights to bf16 ----------------
__global__ __launch_bounds__(256) void k_prep(const float* __restrict__ W,
                                              const float* __restrict__ fcW,
                                              ushort* __restrict__ Wt,
                                              ushort* __restrict__ fcWt) {
    int t = blockIdx.x * 256 + threadIdx.x;
    for (int i = t; i < DHID * DIN; i += gridDim.x * 256) {   // Wt[n][k]
        int n = i >> 8, k = i & 255;
        Wt[i] = f2bf(W[k * DHID + n]);
    }
    for (int i = t; i < NCLS * DHID; i += gridDim.x * 256) {  // fcWt[n][k]
        int n = i >> 7, k = i & 127;
        fcWt[i] = f2bf(fcW[k * NCLS + n]);
    }
}

// ---------------- GEMM1: featb = bf16(X) @ bf16(W), MFMA, pipelined ----------------
// 256 thr (4 waves), tile 128 rows x 128 cols, BK=64, double-buffered LDS (64 KB
// -> 2 blocks/CU). Next chunk staged to regs during MFMA (issue-early/write-late).
__global__ __launch_bounds__(256, 2) void gemm1(const float* __restrict__ X,
                                                const ushort* __restrict__ Wt,
                                                ushort* __restrict__ featb) {
    __shared__ ushort Xs[2][128 * 64];   // 2 x 16 KB, [row][k] swizzled
    __shared__ ushort Wl[2][128 * 64];   // 2 x 16 KB, [n][k] swizzled
    const int t = threadIdx.x;
    const int row0 = blockIdx.x * 128;

    // physical 16B slot -> logical (row, byte-in-row) mapping (same for X and W)
    int srow[4], ske[4];
#pragma unroll
    for (int i = 0; i < 4; i++) {
        int o = i * 4096 + t * 16;
        int row = o >> 7;
        int bl = (o & 127) ^ ((row & 7) << 4);
        srow[i] = row;
        ske[i] = bl >> 1;          // element offset within chunk (0..56)
    }

    float4 xr[4][2];
    uint4  wr[4];

    // ---- issue chunk 0 ----
#pragma unroll
    for (int i = 0; i < 4; i++) {
        int grow = row0 + srow[i];
        if (grow < NN) {
            const float4* p = (const float4*)(X + (size_t)grow * DIN + ske[i]);
            xr[i][0] = p[0]; xr[i][1] = p[1];
        } else {
            xr[i][0] = make_float4(0.f, 0.f, 0.f, 0.f);
            xr[i][1] = make_float4(0.f, 0.f, 0.f, 0.f);
        }
        wr[i] = *(const uint4*)(Wt + (size_t)srow[i] * DIN + ske[i]);
    }
    // ---- commit chunk 0 ----
#pragma unroll
    for (int i = 0; i < 4; i++) {
        int o = i * 4096 + t * 16;
        ushort8v b;
        b[0] = f2bf(xr[i][0].x); b[1] = f2bf(xr[i][0].y);
        b[2] = f2bf(xr[i][0].z); b[3] = f2bf(xr[i][0].w);
        b[4] = f2bf(xr[i][1].x); b[5] = f2bf(xr[i][1].y);
        b[6] = f2bf(xr[i][1].z); b[7] = f2bf(xr[i][1].w);
        *(ushort8v*)((char*)&Xs[0][0] + o) = b;
        *(uint4*)((char*)&Wl[0][0] + o) = wr[i];
    }
    __syncthreads();

    const int w = t >> 6, lane = t & 63;
    const int rbase = w * 32;
    const int lcol = lane & 15;
    const int kgrp = (lane >> 4) * 16;

    f32x4 acc[2][8];
#pragma unroll
    for (int r = 0; r < 2; r++)
#pragma unroll
        for (int c = 0; c < 8; c++) acc[r][c] = (f32x4){0.f, 0.f, 0.f, 0.f};

    for (int c = 0; c < 4; c++) {
        const int buf = c & 1;
        if (c < 3) {   // issue next chunk's global loads (in flight during MFMA)
            int k0g = (c + 1) * 64;
#pragma unroll
            for (int i = 0; i < 4; i++) {
                int grow = row0 + srow[i];
                if (grow < NN) {
                    const float4* p = (const float4*)(X + (size_t)grow * DIN + k0g + ske[i]);
                    xr[i][0] = p[0]; xr[i][1] = p[1];
                } else {
                    xr[i][0] = make_float4(0.f, 0.f, 0.f, 0.f);
                    xr[i][1] = make_float4(0.f, 0.f, 0.f, 0.f);
                }
                wr[i] = *(const uint4*)(Wt + (size_t)srow[i] * DIN + k0g + ske[i]);
            }
        }
        // compute on buf
        const char* xb = (const char*)&Xs[buf][0];
        const char* wb = (const char*)&Wl[buf][0];
#pragma unroll
        for (int k0 = 0; k0 < 2; k0++) {
            int kb = k0 * 64 + kgrp;
            bf16x8 a[2], b[8];
#pragma unroll
            for (int r = 0; r < 2; r++) {
                int row = rbase + r * 16 + lcol;
                a[r] = *(const bf16x8*)(xb + row * 128 + (kb ^ ((row & 7) << 4)));
            }
#pragma unroll
            for (int cc = 0; cc < 8; cc++) {
                int n = cc * 16 + lcol;
                b[cc] = *(const bf16x8*)(wb + n * 128 + (kb ^ ((n & 7) << 4)));
            }
#pragma unroll
            for (int r = 0; r < 2; r++)
#pragma unroll
                for (int cc = 0; cc < 8; cc++)
                    acc[r][cc] = __builtin_amdgcn_mfma_f32_16x16x32_bf16(a[r], b[cc], acc[r][cc], 0, 0, 0);
        }
        if (c < 3) {   // commit next chunk to other buffer
#pragma unroll
            for (int i = 0; i < 4; i++) {
                int o = i * 4096 + t * 16;
                ushort8v b;
                b[0] = f2bf(xr[i][0].x); b[1] = f2bf(xr[i][0].y);
                b[2] = f2bf(xr[i][0].z); b[3] = f2bf(xr[i][0].w);
                b[4] = f2bf(xr[i][1].x); b[5] = f2bf(xr[i][1].y);
                b[6] = f2bf(xr[i][1].z); b[7] = f2bf(xr[i][1].w);
                *(ushort8v*)((char*)&Xs[buf ^ 1][0] + o) = b;
                *(uint4*)((char*)&Wl[buf ^ 1][0] + o) = wr[i];
            }
        }
        __syncthreads();
    }

    // epilogue: stage bf16 tile (reuses Xs: 2*16KB = exactly 128x128 bf16)
    ushort* Os = (ushort*)Xs;
#pragma unroll
    for (int r = 0; r < 2; r++)
#pragma unroll
        for (int cc = 0; cc < 8; cc++)
#pragma unroll
            for (int i = 0; i < 4; i++) {
                int rloc = rbase + r * 16 + (lane >> 4) * 4 + i;
                int col = cc * 16 + lcol;
                Os[rloc * 128 + col] = f2bf(acc[r][cc][i]);
            }
    __syncthreads();
#pragma unroll
    for (int i = 0; i < 8; i++) {
        int u = i * 256 + t;
        int row = u >> 4;
        int grow = row0 + row;
        if (grow < NN)
            *(uint4*)(featb + (size_t)grow * 128 + (u & 15) * 8) =
                *(uint4*)((char*)Os + u * 16);
    }
}

// ---------------- el/er from bf16 feat ----------------
__global__ __launch_bounds__(256) void eler_b(const ushort* __restrict__ featb,
                                              const float* __restrict__ attn_l,
                                              const float* __restrict__ attn_r,
                                              float* __restrict__ el,
                                              float* __restrict__ er) {
    int n = blockIdx.x * 4 + threadIdx.x / 64;
    int lane = threadIdx.x & 63;
    if (n >= NN) return;
    ushort2 f = ((const ushort2*)(featb + (size_t)n * DHID))[lane];
    float f0 = bf2f(f.x), f1 = bf2f(f.y);
    float2 al = ((const float2*)attn_l)[lane];
    float2 ar = ((const float2*)attn_r)[lane];
    float pl = f0 * al.x + f1 * al.y;
    float pr = f0 * ar.x + f1 * ar.y;
#pragma unroll
    for (int off = 32; off; off >>= 1) {
        pl += __shfl_down(pl, off);
        pr += __shfl_down(pr, off);
    }
    if (lane == 0) { el[n] = pl; er[n] = pr; }
}

// ---------------- fused softmax + aggregate: one wave per dst node ----------------
__global__ __launch_bounds__(256) void aggregate(const int* __restrict__ off,
                                                 const int* __restrict__ deg,
                                                 const int* __restrict__ ssrc,
                                                 const float* __restrict__ el,
                                                 const float* __restrict__ er,
                                                 const ushort* __restrict__ featb,
                                                 ushort* __restrict__ hb) {
    int d = blockIdx.x * 4 + threadIdx.x / 64;
    int lane = threadIdx.x & 63;
    if (d >= NN) return;
    int start = off[d];
    int dg = deg[d];
    float erd = er[d];

    float m = -INFINITY;
    for (int j = lane; j < dg; j += 64) {
        int s = ssrc[start + j];
        float x = el[s] + erd;
        float e = x > 0.f ? x : NEG_SLOPE * x;
        m = fmaxf(m, e);
    }
#pragma unroll
    for (int o = 32; o; o >>= 1) m = fmaxf(m, __shfl_xor(m, o));

    float2 acc = make_float2(0.f, 0.f);
    float denom = 0.f;
    for (int c = 0; c < dg; c += 64) {
        int j = c + lane;
        float wv = 0.f;
        int s = 0;
        if (j < dg) {
            s = ssrc[start + j];
            float x = el[s] + erd;
            float e = x > 0.f ? x : NEG_SLOPE * x;
            wv = expf(e - m);
        }
        float wsum = wv;
#pragma unroll
        for (int o = 32; o; o >>= 1) wsum += __shfl_xor(wsum, o);
        denom += wsum;

        int rem = dg - c;
        if (rem > 64) rem = 64;
        int jj = 0;
        for (; jj + 1 < rem; jj += 2) {
            float w0 = __shfl(wv, jj), w1 = __shfl(wv, jj + 1);
            int s0 = __shfl(s, jj), s1 = __shfl(s, jj + 1);
            ushort2 g0 = ((const ushort2*)(featb + (size_t)s0 * DHID))[lane];
            ushort2 g1 = ((const ushort2*)(featb + (size_t)s1 * DHID))[lane];
            acc.x += w0 * bf2f(g0.x) + w1 * bf2f(g1.x);
            acc.y += w0 * bf2f(g0.y) + w1 * bf2f(g1.y);
        }
        if (jj < rem) {
            float w0 = __shfl(wv, jj);
            int s0 = __shfl(s, jj);
            ushort2 g0 = ((const ushort2*)(featb + (size_t)s0 * DHID))[lane];
            acc.x += w0 * bf2f(g0.x);
            acc.y += w0 * bf2f(g0.y);
        }
    }
    float inv = (dg > 0) ? 1.0f / denom : 0.f;
    ushort2 o2;
    o2.x = f2bf(acc.x * inv);
    o2.y = f2bf(acc.y * inv);
    ((ushort2*)(hb + (size_t)d * DHID))[lane] = o2;
}

// ---------------- GEMM2: out = bf16(h) @ bf16(fcW) + fcb, MFMA ----------------
__global__ __launch_bounds__(256) void gemm2(const ushort* __restrict__ hb,
                                             const ushort* __restrict__ fcWt,
                                             const float* __restrict__ fcb,
                                             float* __restrict__ out) {
    __shared__ ushort Hs[128 * 128];
    __shared__ ushort Fs[64 * 128];
    __shared__ float  Os[128 * 64];
    const int t = threadIdx.x;
    const int row0 = blockIdx.x * 128;

    {
#pragma unroll
        for (int i = 0; i < 8; i++) {
            int u = i * 256 + t;
            int row = u >> 4;
            int grow = row0 + row;
            uint4 v = make_uint4(0, 0, 0, 0);
            if (grow < NN) v = *(const uint4*)(hb + (size_t)grow * 128 + (u & 15) * 8);
            int byte_off = row * 256 + (((u & 15) * 16) ^ ((row & 7) << 4));
            *(uint4*)((char*)Hs + byte_off) = v;
        }
#pragma unroll
        for (int i = 0; i < 4; i++) {
            int u = i * 256 + t;
            int n = u >> 4;
            int byte_off = n * 256 + (((u & 15) * 16) ^ ((n & 7) << 4));
            *(uint4*)((char*)Fs + byte_off) = ((const uint4*)fcWt)[u];
        }
    }
    __syncthreads();

    const int w = t >> 6, lane = t & 63;
    const int rbase = w * 32;
    const int lcol = lane & 15;
    const int kgrp = (lane >> 4) * 16;

    f32x4 acc[2][4];
#pragma unroll
    for (int r = 0; r < 2; r++)
#pragma unroll
        for (int c = 0; c < 4; c++) acc[r][c] = (f32x4){0.f, 0.f, 0.f, 0.f};

#pragma unroll
    for (int k0 = 0; k0 < 4; k0++) {
        int kbyte = k0 * 64 + kgrp;
        bf16x8 a[2], b[4];
#pragma unroll
        for (int r = 0; r < 2; r++) {
            int row = rbase + r * 16 + lcol;
            a[r] = *(bf16x8*)((char*)Hs + row * 256 + (kbyte ^ ((row & 7) << 4)));
        }
#pragma unroll
        for (int c = 0; c < 4; c++) {
            int n = c * 16 + lcol;
            b[c] = *(bf16x8*)((char*)Fs + n * 256 + (kbyte ^ ((n & 7) << 4)));
        }
#pragma unroll
        for (int r = 0; r < 2; r++)
#pragma unroll
            for (int c = 0; c < 4; c++)
                acc[r][c] = __builtin_amdgcn_mfma_f32_16x16x32_bf16(a[r], b[c], acc[r][c], 0, 0, 0);
    }

#pragma unroll
    for (int r = 0; r < 2; r++)
#pragma unroll
        for (int c = 0; c < 4; c++) {
            int col = c * 16 + lcol;
            float bias = fcb[col];
#pragma unroll
            for (int i = 0; i < 4; i++) {
                int rloc = rbase + r * 16 + (lane >> 4) * 4 + i;
                Os[rloc * 64 + col] = acc[r][c][i] + bias;
            }
        }
    __syncthreads();
#pragma unroll
    for (int i = 0; i < 8; i++) {
        int u = i * 256 + t;
        int row = u >> 4;
        int grow = row0 + row;
        if (grow < NN)
            *(float4*)(out + (size_t)grow * 64 + (u & 15) * 4) = ((float4*)Os)[u];
    }
}

// ---------------- launch ----------------
extern "C" void kernel_launch(void* const* d_in, const int* in_sizes, int n_in,
                              void* d_out, int out_size, void* d_ws, size_t ws_size,
                              hipStream_t stream) {
    const float* X      = (const float*)d_in[0];
    const float* W      = (const float*)d_in[1];
    const float* attn_l = (const float*)d_in[2];
    const float* attn_r = (const float*)d_in[3];
    const float* fcW    = (const float*)d_in[4];
    const float* fcb    = (const float*)d_in[5];
    const int*   src    = (const int*)d_in[6];
    const int*   dst    = (const int*)d_in[7];
    float* out = (float*)d_out;

    char* ws = (char*)d_ws;
    ushort* featb = (ushort*)ws;            ws += (size_t)NN * DHID * 2;
    ushort* hb    = (ushort*)ws;            ws += (size_t)NN * DHID * 2;
    ushort* Wt    = (ushort*)ws;            ws += (size_t)DHID * DIN * 2;
    ushort* fcWt  = (ushort*)ws;            ws += (size_t)NCLS * DHID * 2;
    float* el     = (float*)ws;             ws += (size_t)NN * 4;
    float* er     = (float*)ws;             ws += (size_t)NN * 4;
    int*   deg    = (int*)ws;               ws += (size_t)NN * 4;
    int*   off    = (int*)ws;               ws += (size_t)NN * 4;
    int*   ssrc   = (int*)ws;               ws += (size_t)NE * 4;
    unsigned* ebuf = (unsigned*)ws;         ws += (size_t)NE * 4;
    int*   ghist  = (int*)ws;               ws += (size_t)256 * 4;
    int*   boff   = (int*)ws;               ws += (size_t)256 * 4;
    int*   gcur   = (int*)ws;               ws += (size_t)256 * 4;

    hipMemsetAsync(ghist, 0, NBUCK * sizeof(int), stream);

    // CSR build (bucketed counting sort)
    k_ghist<<<NCHB, 256, 0, stream>>>(dst, ghist);
    k_prep<<<64, 256, 0, stream>>>(W, fcW, Wt, fcWt);
    k_gscan<<<1, 256, 0, stream>>>(ghist, boff, gcur);
    k_bin<<<NCHB, 256, 0, stream>>>(src, dst, gcur, ebuf);
    k_csr<<<NBUCK, 256, 0, stream>>>(ebuf, boff, off, deg, ssrc);

    // dense pipeline (bf16 MFMA)
    gemm1<<<(NN + 127) / 128, 256, 0, stream>>>(X, Wt, featb);
    eler_b<<<(NN + 3) / 4, 256, 0, stream>>>(featb, attn_l, attn_r, el, er);
    aggregate<<<(NN + 3) / 4, 256, 0, stream>>>(off, deg, ssrc, el, er, featb, hb);
    gemm2<<<(NN + 127) / 128, 256, 0, stream>>>(hb, fcWt, fcb, out);
}